// Round 1
// 4151.833 us; speedup vs baseline: 1.1774x; 1.1774x over previous
//
#include <hip/hip_runtime.h>

// ---------------------------------------------------------------------------
// PolicyNetRSNNPB forward, MI355X/gfx950.  Round 10: fill the issue slots.
// r9 passed (4.89 ms; k_rec 4.46 ms = 8.7 us/step). rocprof: VALUBusy 71%,
// Occupancy 11.5% (1 wave/SIMD) -> k_rec is VALU-issue-bound with ~29%
// exposed stalls (ds_read/XW latency + tag-poll) and nothing co-resident to
// hide them. Arithmetic FROZEN (numpy-fp32 emulation): seq-k FMA ascending
// per accumulator, K=512 split [0,384)+[384,512) merged by one fadd;
// elementwise single-rounded, no contraction. This round changes ONLY the
// k_rec execution shape:
//   (1) 256 blocks x 512 THREADS (8 waves = 4 rec + 4 ff, 2 waves/SIMD);
//       each thread owns 1 output row (was 2). Same total issue, stalls
//       cross-hidden by the co-resident wave.
//   (2) Staging: 1 ring word per thread (was 2 serialized polls) -> single
//       LLC flight. Bits stored as u16, read as u32 ([2][16][34] u16).
//   (3) XW loaded only on even tp (reference reuses x across REPEAT=2;
//       value-identical) -> half the per-step global-load latency events.
//   (4) Tags 1-based (tag = tp+1) so zeroed/poisoned ring words can never
//       false-match at tp=1. Slot-reuse induction unchanged: producer at
//       tp+2 requires all tags tp+1, which requires every member block
//       passed its barrier at tp+1, which requires all waves consumed tp.
// k_prepT/k_xw/k_c3/k_scan/k_out and the workspace layout unchanged from r9.
// ---------------------------------------------------------------------------

typedef unsigned int       u32;
typedef unsigned short     u16;
typedef unsigned long long u64;
typedef unsigned char      u8;

#define TSTEPS 512
#define HIDDEN 512

// workspace layout (bytes) — unchanged from r7/r8/r9.
#define XW_OFF    0ull
#define C3_OFF    0ull
#define MEM_OFF   33554432ull
#define SPKB_OFF  100663296ull
#define WT_OFF    109051904ull
#define WINT_OFF  109314048ull
#define RING_OFF  134217728ull
#define CNT_OFF   134742016ull
#define WS_NEED   (134742016ull + 4096ull)

#define QCHUNK 384

// ---------------------------------------------------------------------------
__global__ __launch_bounds__(256) void k_prepT(
    const float* __restrict__ Win,
    const float* __restrict__ Wmu, const float* __restrict__ Wlv,
    float* __restrict__ WinT, float* __restrict__ WT)
{
  const int idx = blockIdx.x * 256 + threadIdx.x;
  if (idx < 65536) {
    const int k = idx >> 9, j = idx & 511;
    WinT[idx] = Win[j * 128 + k];
  } else {
    const int i2 = idx - 65536;
    const int k = i2 >> 7, j = i2 & 127;
    WT[i2] = (j < 64) ? Wmu[j * 512 + k] : Wlv[(j - 64) * 512 + k];
  }
}

// ---------------------------------------------------------------------------
__global__ __launch_bounds__(256) void k_xw(
    const float* __restrict__ state, const float* __restrict__ target,
    const float* __restrict__ WinT, const float* __restrict__ b_in,
    float* __restrict__ XW)
{
  __shared__ float xs[16][129];
  const int tid  = threadIdx.x;
  const int row0 = blockIdx.x * 16;

  for (int e = tid; e < 2048; e += 256) {
    int r = e >> 7, k = e & 127;
    xs[r][k] = (k < 64) ? state[(row0 + r) * 64 + k]
                        : target[(row0 + r) * 64 + k - 64];
  }
  __syncthreads();

#pragma unroll
  for (int jh = 0; jh < 2; ++jh) {
    const int j = jh * 256 + tid;
    float acc[16];
#pragma unroll
    for (int r = 0; r < 16; ++r) acc[r] = 0.0f;
    for (int k = 0; k < 128; ++k) {
      const float wv = WinT[k * 512 + j];
#pragma unroll
      for (int r = 0; r < 16; ++r)
        acc[r] = __builtin_fmaf(xs[r][k], wv, acc[r]);
    }
    const float b = b_in[j];
#pragma unroll
    for (int r = 0; r < 16; ++r)
      XW[(row0 + r) * 512 + j] = __fadd_rn(acc[r], b);
  }
}

// ---------------------------------------------------------------------------
// k_rec: grid 256 = 8 groups x 32 members, block 512 = 8 waves (2/SIMD).
// Waves 0-3: rec GEMM+epilogue (tagged ring stores, 1-based tags).
// Waves 4-7: ff GEMM+epilogue (spkb32 history, format unchanged).
// Lane = (rloc, ch) -> 1 row of one matrix. Each SIMD hosts one rec wave and
// one ff wave: their ds_read/global-load/poll stalls cross-hide.
// Sync: per-word tag polling (1 word/thread) + one __syncthreads per step
// (Bits double-buffered by step parity).
// ---------------------------------------------------------------------------
__global__ __launch_bounds__(512, 2) void k_rec(
    const float* __restrict__ XW,
    const float* __restrict__ Wrec, const float* __restrict__ Wff,
    const float* __restrict__ alpha_rec, const float* __restrict__ beta_rec,
    const float* __restrict__ b_rec,
    const float* __restrict__ b_ff, const float* __restrict__ alpha_ff,
    const float* __restrict__ beta_ff,
    u32* __restrict__ ring32, u32* __restrict__ spkb32)
{
  __shared__ float WR[16 * 516];       // 33024 B
  __shared__ float WF[16 * 516];       // 33024 B
  __shared__ u32   BitsW[2][16][17];   // u32 view; staged as u16 halves

  const int tid  = threadIdx.x;
  const int g    = blockIdx.x & 7;
  const int c    = blockIdx.x >> 3;          // 0..31 (16 channels each)
  const int n0   = g * 16;
  const int wv   = tid >> 6;                 // 0..7
  const int lane = tid & 63;
  const int ch   = lane & 15;                // channel within member
  const int rloc = lane >> 4;                // 0..3
  const int row  = (wv & 3) * 4 + rloc;      // 0..15 within group
  const bool isFF = (wv >= 4);
  const int jj   = c * 16 + ch;              // global hidden unit

  for (int it = tid; it < 2048; it += 512) {
    const int r16 = it >> 7, k4 = (it & 127) * 4;
    *(float4*)(WR + r16 * 516 + k4) = *(const float4*)(Wrec + (c * 16 + r16) * 512 + k4);
    *(float4*)(WF + r16 * 516 + k4) = *(const float4*)(Wff  + (c * 16 + r16) * 512 + k4);
  }

  float coA, coB, coC;
  if (!isFF) { coA = alpha_rec[jj]; coB = beta_rec[jj]; coC = b_rec[jj]; }
  else       { coA = alpha_ff[jj];  coB = beta_ff[jj];  coC = b_ff[jj]; }

  float syn = 0.f, mem = 0.f, spk = 0.f, xw = 0.f;

  const float* wp = (isFF ? WF : WR) + ch * 516;
  const int srow = tid >> 5;    // 0..15 : staged row
  const int sjl  = tid & 31;    // 0..31 : staged ring word (u16 half)

  __syncthreads();  // weights ready

  for (int tp = 0; tp <= TSTEPS; ++tp) {
    // XW reused for both repeats of a t_step (reference passes the same x
    // to both neuron_step calls) — load once per pair, value-identical.
    if (!isFF && tp < TSTEPS && !(tp & 1))
      xw = XW[((tp >> 1) * 128 + n0 + row) * 512 + jj];

    float SA = 0.f;

    if (tp > 0) {
      const int bp = (tp - 1) & 1;
      { // stage spike bits of step tp-1: 1 tagged word per thread (tag = tp)
        const u32 expct = (u32)tp;
        const u32* src = ring32 + (bp * 128 + n0 + srow) * 32 + sjl;
        u32 m = __hip_atomic_load(src, __ATOMIC_RELAXED, __HIP_MEMORY_SCOPE_AGENT);
        while ((m >> 16) != expct) {
          __builtin_amdgcn_s_sleep(1);
          m = __hip_atomic_load(src, __ATOMIC_RELAXED, __HIP_MEMORY_SCOPE_AGENT);
        }
        ((u16*)BitsW[bp][srow])[sjl] = (u16)m;   // low 16 bits = mask
      }
      __syncthreads();   // Bits[bp] complete; bounds skew for dbuf reuse

      if (isFF || tp < TSTEPS) {
        // BLAS-faithful GEMM: seq-FMA ascending k, chunk split at kb=12.
        float aA = 0.f, aB = 0.f;
        for (int kb = 0; kb < 12; ++kb) {
          const u32 w0 = BitsW[bp][row][kb];
#pragma unroll
          for (int k4 = 0; k4 < 32; k4 += 4) {
            const float4 w4 = *(const float4*)(wp + kb * 32 + k4);
#pragma unroll
            for (int i = 0; i < 4; ++i) {
              const float wvv = (i == 0) ? w4.x : (i == 1) ? w4.y : (i == 2) ? w4.z : w4.w;
              aA = __builtin_fmaf((float)((w0 >> (k4 + i)) & 1u), wvv, aA);
            }
          }
        }
        for (int kb = 12; kb < 16; ++kb) {
          const u32 w0 = BitsW[bp][row][kb];
#pragma unroll
          for (int k4 = 0; k4 < 32; k4 += 4) {
            const float4 w4 = *(const float4*)(wp + kb * 32 + k4);
#pragma unroll
            for (int i = 0; i < 4; ++i) {
              const float wvv = (i == 0) ? w4.x : (i == 1) ? w4.y : (i == 2) ? w4.z : w4.w;
              aB = __builtin_fmaf((float)((w0 >> (k4 + i)) & 1u), wvv, aB);
            }
          }
        }
        SA = __fadd_rn(aA, aB);
      }
    }

    if (isFF) {
      if (tp > 0) {
        // ff epilogue for step tp-1
        float curf = __fadd_rn(SA, coC);
        syn = __fadd_rn(__fmul_rn(coA, syn), curf);
        mem = __fsub_rn(__fadd_rn(__fmul_rn(coB, mem), syn), spk);
        spk = (mem > 1.0f) ? 1.0f : 0.0f;
        const u64 B = __ballot(spk != 0.f);
        if (ch == 0) {
          spkb32[((u64)(tp - 1) * 128 + n0 + row) * 32 + c] =
              (u32)((B >> (16 * rloc)) & 0xFFFFull);
        }
      }
    } else {
      if (tp < TSTEPS) {
        // rec epilogue for step tp; tagged ring store (tag = tp+1, 1-based)
        float cur = __fadd_rn(__fadd_rn(xw, SA), coC);
        syn = __fadd_rn(__fmul_rn(coA, syn), cur);
        mem = __fsub_rn(__fadd_rn(__fmul_rn(coB, mem), syn), spk);
        spk = (mem > 1.0f) ? 1.0f : 0.0f;
        const u64 B = __ballot(spk != 0.f);
        if (ch == 0) {
          const u32 tag = ((u32)(tp + 1)) << 16;
          __hip_atomic_store(ring32 + ((tp & 1) * 128 + n0 + row) * 32 + c,
                             tag | (u32)((B >> (16 * rloc)) & 0xFFFFull),
                             __ATOMIC_RELAXED, __HIP_MEMORY_SCOPE_AGENT);
        }
      }
    }
    // no end-of-step barrier: Bits is double-buffered; the pre-GEMM barrier
    // bounds inter-wave skew to one step.
  }
}

// ---------------------------------------------------------------------------
__global__ __launch_bounds__(256) void k_c3(
    const u32* __restrict__ spkb32, const float* __restrict__ WT,
    const float* __restrict__ bmu, const float* __restrict__ blv,
    float* __restrict__ c3)
{
  __shared__ u32 Bc[32][32];
  const int tid  = threadIdx.x;
  const int rows0 = blockIdx.x * 32;

  for (int it = tid; it < 1024; it += 256)
    ((u32*)Bc)[it] = spkb32[(u64)rows0 * 32 + it];
  __syncthreads();

  const int j  = tid & 127;
  const int rh = tid >> 7;
  const float bias = (j < 64) ? bmu[j] : blv[j - 64];

  float accA[16], accB[16];
#pragma unroll
  for (int r = 0; r < 16; ++r) { accA[r] = 0.f; accB[r] = 0.f; }

  for (int m = 0; m < 24; ++m) {
    u32 wrow[16];
#pragma unroll
    for (int r = 0; r < 16; ++r) wrow[r] = Bc[rh * 16 + r][m];
    const float* wpp = WT + (m * 16) * 128 + j;
#pragma unroll
    for (int kk = 0; kk < 16; ++kk) {
      const float wvv = wpp[kk * 128];
#pragma unroll
      for (int r = 0; r < 16; ++r) {
        const float b = (float)((wrow[r] >> kk) & 1u);
        accA[r] = __builtin_fmaf(b, wvv, accA[r]);
      }
    }
  }
  for (int m = 24; m < 32; ++m) {
    u32 wrow[16];
#pragma unroll
    for (int r = 0; r < 16; ++r) wrow[r] = Bc[rh * 16 + r][m];
    const float* wpp = WT + (m * 16) * 128 + j;
#pragma unroll
    for (int kk = 0; kk < 16; ++kk) {
      const float wvv = wpp[kk * 128];
#pragma unroll
      for (int r = 0; r < 16; ++r) {
        const float b = (float)((wrow[r] >> kk) & 1u);
        accB[r] = __builtin_fmaf(b, wvv, accB[r]);
      }
    }
  }

#pragma unroll
  for (int r = 0; r < 16; ++r)
    c3[(u64)(rows0 + rh * 16 + r) * 128 + j] =
        __fadd_rn(__fadd_rn(accA[r], accB[r]), bias);
}

// ---------------------------------------------------------------------------
__global__ __launch_bounds__(256) void k_scan(
    const float* __restrict__ c3,
    const float* __restrict__ beta_mu, const float* __restrict__ beta_lv,
    float* __restrict__ Mem)
{
  const int tid = blockIdx.x * 256 + threadIdx.x;
  const int n = tid >> 7, ap = tid & 127;
  const float beta = (ap < 64) ? beta_mu[ap] : beta_lv[ap - 64];
  const float* src = c3 + n * 128 + ap;
  float* dst = Mem + n * 128 + ap;
  float mem = 0.0f;
  for (int t = 0; t < 512; ++t) {
    mem = __fadd_rn(__fmul_rn(beta, mem), src[(u64)t * 16384]);
    dst[(u64)t * 16384] = mem;
  }
}

// ---------------------------------------------------------------------------
__global__ __launch_bounds__(256) void k_out(
    const float* __restrict__ Mem,
    const float* __restrict__ Wmu_out, const float* __restrict__ Wlv_out,
    float* __restrict__ out)
{
  const int tid = blockIdx.x * 256 + threadIdx.x;
  const int a = tid & 7;
  const int n = (tid >> 3) & 127;
  const int t = (tid >> 10) & 255;
  const int kind = tid >> 18;
  const float* wv = ((kind == 0) ? Wmu_out : Wlv_out) + a * 64;
  const float* s0 = Mem + ((u64)(2 * t) * 128 + n) * 128 + kind * 64;
  const float* s1 = Mem + ((u64)(2 * t + 1) * 128 + n) * 128 + kind * 64;
  float mu0 = 0.0f, mu1 = 0.0f;
#pragma unroll 8
  for (int q = 0; q < 64; ++q) mu0 = __builtin_fmaf(s0[q], wv[q], mu0);
#pragma unroll 8
  for (int q = 0; q < 64; ++q) mu1 = __builtin_fmaf(s1[q], wv[q], mu1);
  out[tid] = __fmul_rn(__fadd_rn(mu0, mu1), 0.5f);
}

// ---------------------------------------------------------------------------
extern "C" void kernel_launch(void* const* d_in, const int* in_sizes, int n_in,
                              void* d_out, int out_size, void* d_ws, size_t ws_size,
                              hipStream_t stream) {
  (void)in_sizes; (void)n_in; (void)out_size;
  if (ws_size < WS_NEED) return;

  const float* state     = (const float*)d_in[0];
  const float* target    = (const float*)d_in[1];
  const float* W_rec_in  = (const float*)d_in[2];
  const float* b_rec_in  = (const float*)d_in[3];
  const float* W_rec     = (const float*)d_in[4];
  const float* b_rec     = (const float*)d_in[5];
  const float* alpha_rec = (const float*)d_in[6];
  const float* beta_rec  = (const float*)d_in[7];
  const float* W_ff_in   = (const float*)d_in[8];
  const float* b_ff_in   = (const float*)d_in[9];
  const float* alpha_ff  = (const float*)d_in[10];
  const float* beta_ff   = (const float*)d_in[11];
  const float* W_mu_in   = (const float*)d_in[12];
  const float* b_mu_in   = (const float*)d_in[13];
  const float* beta_mu   = (const float*)d_in[14];
  const float* W_mu_out  = (const float*)d_in[15];
  const float* W_lv_in   = (const float*)d_in[16];
  const float* b_lv_in   = (const float*)d_in[17];
  const float* beta_lv   = (const float*)d_in[18];
  const float* W_lv_out  = (const float*)d_in[19];

  char* ws = (char*)d_ws;
  float* XW    = (float*)(ws + XW_OFF);
  float* c3    = (float*)(ws + C3_OFF);
  float* Mem   = (float*)(ws + MEM_OFF);
  u32*   spkb32= (u32*)  (ws + SPKB_OFF);
  float* WT    = (float*)(ws + WT_OFF);
  float* WinT  = (float*)(ws + WINT_OFF);
  u32*   ring32= (u32*)  (ws + RING_OFF);

  hipLaunchKernelGGL(k_prepT, dim3(512), dim3(256), 0, stream,
                     W_rec_in, W_mu_in, W_lv_in, WinT, WT);
  hipLaunchKernelGGL(k_xw, dim3(2048), dim3(256), 0, stream,
                     state, target, WinT, b_rec_in, XW);
  hipLaunchKernelGGL(k_rec, dim3(256), dim3(512), 0, stream,
                     XW, W_rec, W_ff_in,
                     alpha_rec, beta_rec, b_rec,
                     b_ff_in, alpha_ff, beta_ff, ring32, spkb32);
  hipLaunchKernelGGL(k_c3, dim3(2048), dim3(256), 0, stream,
                     spkb32, WT, b_mu_in, b_lv_in, c3);
  hipLaunchKernelGGL(k_scan, dim3(64), dim3(256), 0, stream,
                     c3, beta_mu, beta_lv, Mem);
  hipLaunchKernelGGL(k_out, dim3(2048), dim3(256), 0, stream,
                     Mem, W_mu_out, W_lv_out, (float*)d_out);
}